// Round 1
// baseline (1319.787 us; speedup 1.0000x reference)
//
#include <hip/hip_runtime.h>
#include <math.h>

// Problem constants (from reference): x [8,128,512,512] f32, 16 segments of 128x128.
#define B_    8
#define C_    128
#define H_    512
#define W_    512
#define HW_   (H_ * W_)        // 262144 = 2^18
#define NSEG_ 16
#define TS_   128              // tile side
#define SGRID_ 4               // 4x4 tile grid

// Kernel 1: per-pixel L2 norm over channel dim.
// Each thread handles 4 consecutive-w pixels via float4; loops over 128 channels
// (stride HW_ between channels -> every wave load is a coalesced contiguous row).
__global__ __launch_bounds__(256) void l2norm_kernel(const float* __restrict__ x,
                                                     float* __restrict__ l2) {
    int t = blockIdx.x * blockDim.x + threadIdx.x;   // 0 .. B*HW/4-1
    int q = t << 2;                                  // flat pixel index (x4)
    int b = q >> 18;                                 // q / HW_
    int hw = q & (HW_ - 1);
    const float* p = x + (size_t)b * C_ * HW_ + hw;
    float s0 = 0.f, s1 = 0.f, s2 = 0.f, s3 = 0.f;
#pragma unroll 8
    for (int c = 0; c < C_; ++c) {
        float4 v = *reinterpret_cast<const float4*>(p + (size_t)c * HW_);
        s0 = fmaf(v.x, v.x, s0);
        s1 = fmaf(v.y, v.y, s1);
        s2 = fmaf(v.z, v.z, s2);
        s3 = fmaf(v.w, v.w, s3);
    }
    float4 r;
    r.x = sqrtf(s0); r.y = sqrtf(s1); r.z = sqrtf(s2); r.w = sqrtf(s3);
    *reinterpret_cast<float4*>(l2 + q) = r;
}

// Kernel 2: per-tile 3x3 conv (zero pad at tile borders) + bias + sigmoid.
// Output flat layout == [b][seg][r][c] row-major (the reference's double reshape
// is a pure flat view). Tile (i,j) of the l2 map -> seg = i*4 + j.
__global__ __launch_bounds__(256) void tileconv_kernel(const float* __restrict__ l2,
                                                       const float* __restrict__ w,
                                                       const float* __restrict__ bias,
                                                       float* __restrict__ out) {
    int t = blockIdx.x * blockDim.x + threadIdx.x;   // 0 .. B*NSEG*TS*TS-1
    int c   = t & (TS_ - 1);
    int r   = (t >> 7) & (TS_ - 1);
    int seg = (t >> 14) & (NSEG_ - 1);
    int b   = t >> 18;
    int ti = seg >> 2;      // tile row
    int tj = seg & 3;       // tile col

    const float* wp = w + seg * 9;
    float w00 = wp[0], w01 = wp[1], w02 = wp[2];
    float w10 = wp[3], w11 = wp[4], w12 = wp[5];
    float w20 = wp[6], w21 = wp[7], w22 = wp[8];

    const float* base = l2 + (size_t)b * HW_ + (size_t)(ti * TS_) * W_ + tj * TS_;

    float acc = bias[seg];
    bool up = (r > 0), dn = (r < TS_ - 1);
    bool lf = (c > 0), rt = (c < TS_ - 1);

    const float* row0 = base + (r - 1) * W_ + c;
    const float* row1 = row0 + W_;
    const float* row2 = row1 + W_;

    if (up) {
        if (lf) acc = fmaf(row0[-1], w00, acc);
        acc = fmaf(row0[0], w01, acc);
        if (rt) acc = fmaf(row0[1], w02, acc);
    }
    if (lf) acc = fmaf(row1[-1], w10, acc);
    acc = fmaf(row1[0], w11, acc);
    if (rt) acc = fmaf(row1[1], w12, acc);
    if (dn) {
        if (lf) acc = fmaf(row2[-1], w20, acc);
        acc = fmaf(row2[0], w21, acc);
        if (rt) acc = fmaf(row2[1], w22, acc);
    }

    out[t] = 1.0f / (1.0f + expf(-acc));
}

extern "C" void kernel_launch(void* const* d_in, const int* in_sizes, int n_in,
                              void* d_out, int out_size, void* d_ws, size_t ws_size,
                              hipStream_t stream) {
    const float* x      = (const float*)d_in[0];
    const float* conv_w = (const float*)d_in[1];
    const float* conv_b = (const float*)d_in[2];
    float* out = (float*)d_out;
    float* l2  = (float*)d_ws;   // 8*512*512*4 = 8 MB scratch

    // Kernel 1: B*HW/4 threads, 4 pixels each.
    int n1 = B_ * HW_ / 4;                 // 524288
    l2norm_kernel<<<n1 / 256, 256, 0, stream>>>(x, l2);

    // Kernel 2: one thread per output element.
    int n2 = B_ * NSEG_ * TS_ * TS_;       // 2097152
    tileconv_kernel<<<n2 / 256, 256, 0, stream>>>(l2, conv_w, conv_b, out);
}